// Round 15
// baseline (12.222 us; speedup 1.0000x reference)
//
#include <hip/hip_runtime.h>

static constexpr int HID = 64;
static constexpr int M   = 15;            // intervals; knots 0..15
static constexpr int NK  = 16;
static constexpr int H1S = 68;            // h1L stride: 64 + 4 pad (bank spread)
static constexpr int TPB = 512;           // 8 waves = 2/SIMD
static constexpr int OVPT  = 4;           // outputs per thread
static constexpr int OTILE = TPB * OVPT;  // 2048 outputs per block

__device__ __forceinline__ float softplusf(float x) {
  return (x > 20.0f) ? x : log1pf(expf(x));
}

// fast tanh via hardware exp + rcp: tanh(x) = 1 - 2/(e^{2x}+1). rel err ~1e-7.
__device__ __forceinline__ float fast_tanhf(float x) {
  float e = __expf(2.0f * x);
  return 1.0f - 2.0f * __builtin_amdgcn_rcpf(e + 1.0f);
}

// ONE kernel, 245 blocks x 512 threads — R14 structure minus W2 staging,
// GEMM k-split across all 8 waves:
//  1. NO W2 LDS staging: W2 (16 KB) is L1-resident per CU; GEMM reads it
//     directly from global (L1 hit after first touch). Kills the staging
//     phase, its barrier-head latency, and 4 KB of LDS traffic per thread.
//  2. layer 1 on all 512 threads: thread = (knot = tid>>5, k0 = 2*(tid&31)),
//     h1 transposed+padded h1L[knot*68+k], float2 writes.
//  3. layers 2+3 k-SPLIT: thread = (knot kg = tid>>5, half = (tid>>4)&1,
//     units j0 = 4*(tid&15)); each thread sums 32 k-terms (8 kc-iters x
//     (1 h1 b128 + 4 W2 global-b128 + 16 FMA)); halves combined with one
//     shfl_xor(16) per accumulator. 2 waves/SIMD busy throughout.
//  4. 16-lane Picard: 7 half-passes, 4th-order cumulative quadrature,
//     writes Ik[p] = I0*exp(Q_I(t_p) - g*t_p) to LDS.
//  5. all 512 threads: cubic-Lagrange interp of Ik (no exp), float4 stores.
__global__ void __launch_bounds__(TPB)
sir_onekernel(const float* __restrict__ I_init,
              const float* __restrict__ W1, const float* __restrict__ b1,
              const float* __restrict__ W2, const float* __restrict__ b2,
              const float* __restrict__ W3, const float* __restrict__ b3,
              const float* __restrict__ gamma_param,
              float* __restrict__ out, int T) {
  __shared__ float h1L[NK * H1S];    // 4.3 KB, [knot][k] padded
  __shared__ float beta_s[NK];
  __shared__ float Ik[NK];

  const int tid = threadIdx.x;
  const float h = 1.0f / (float)M;

  // ---- layer 1 on all threads: (knot = tid>>5, k0 = 2*(tid&31)) ----
  {
    const int knot = tid >> 5;                 // [0,16)
    const int k0   = (tid & 31) * 2;           // [0,64)
    const float tv = (float)knot * h;
    float2 w1 = *(const float2*)(W1 + k0);
    float2 bb = *(const float2*)(b1 + k0);
    float2 hv;
    hv.x = fast_tanhf(fmaf(tv, w1.x, bb.x));
    hv.y = fast_tanhf(fmaf(tv, w1.y, bb.y));
    *(float2*)(h1L + knot * H1S + k0) = hv;
  }
  __syncthreads();

  // ---- layers 2+3, k-split: (kg = tid>>5, half = (tid>>4)&1, j0) ----
  {
    const int kg   = tid >> 5;          // [0,16)
    const int half = (tid >> 4) & 1;    // k-range half
    const int jq   = tid & 15;
    const int j0   = jq * 4;
    const int kbase = half * 32;
    float z0, z1, z2, z3;
    if (half == 0) {
      float4 bb2 = *(const float4*)(b2 + j0);
      z0 = bb2.x; z1 = bb2.y; z2 = bb2.z; z3 = bb2.w;
    } else {
      z0 = z1 = z2 = z3 = 0.0f;
    }
    const float* h1row = h1L + kg * H1S + kbase;
    const float* w2p   = W2 + kbase * HID + j0;   // direct global (L1-resident)
#pragma unroll 4
    for (int kc = 0; kc < 32; kc += 4) {
      float4 ha  = *(const float4*)(h1row + kc);             // LDS broadcast
      float4 wv0 = *(const float4*)(w2p + (kc + 0) * HID);
      float4 wv1 = *(const float4*)(w2p + (kc + 1) * HID);
      float4 wv2 = *(const float4*)(w2p + (kc + 2) * HID);
      float4 wv3 = *(const float4*)(w2p + (kc + 3) * HID);
      z0 = fmaf(ha.x, wv0.x, z0); z1 = fmaf(ha.x, wv0.y, z1);
      z2 = fmaf(ha.x, wv0.z, z2); z3 = fmaf(ha.x, wv0.w, z3);
      z0 = fmaf(ha.y, wv1.x, z0); z1 = fmaf(ha.y, wv1.y, z1);
      z2 = fmaf(ha.y, wv1.z, z2); z3 = fmaf(ha.y, wv1.w, z3);
      z0 = fmaf(ha.z, wv2.x, z0); z1 = fmaf(ha.z, wv2.y, z1);
      z2 = fmaf(ha.z, wv2.z, z2); z3 = fmaf(ha.z, wv2.w, z3);
      z0 = fmaf(ha.w, wv3.x, z0); z1 = fmaf(ha.w, wv3.y, z1);
      z2 = fmaf(ha.w, wv3.z, z2); z3 = fmaf(ha.w, wv3.w, z3);
    }
    // combine k-halves: lane l <-> l^16 holds the other half of the same kg
    z0 += __shfl_xor(z0, 16); z1 += __shfl_xor(z1, 16);
    z2 += __shfl_xor(z2, 16); z3 += __shfl_xor(z3, 16);
    if (half == 0) {
      float4 w3v = *(const float4*)(W3 + j0);
      float acc = fast_tanhf(z0) * w3v.x + fast_tanhf(z1) * w3v.y
                + fast_tanhf(z2) * w3v.z + fast_tanhf(z3) * w3v.w;
      acc += __shfl_xor(acc, 1);
      acc += __shfl_xor(acc, 2);
      acc += __shfl_xor(acc, 4);
      acc += __shfl_xor(acc, 8);
      if (jq == 0) beta_s[kg] = softplusf(acc + b3[0]);
    }
  }
  __syncthreads();

  // ---- Picard on lanes 0..15 (serial path, others wait) ----
  if (tid < 16) {
    const float I0 = I_init[0];
    const float g  = softplusf(gamma_param[0]);
    const float S0 = 1.0f - I0;
    const int p = tid;
    const float tp = (float)p * h;
    const float bet = beta_s[p];
    const float c24 = h * (1.0f / 24.0f);
    float QA = 0.0f, QB = 0.0f;
    const int im2 = p >= 2 ? p - 2 : 0;
    const int im1 = p >= 1 ? p - 1 : 0;
    const int ip1 = p <= M - 1 ? p + 1 : M;
    const int ip2 = p <= M - 2 ? p + 2 : M;
    const int ip3 = p <= M - 3 ? p + 3 : M;
    for (int ph = 0; ph < 7; ++ph) {
      const bool iPass = (ph & 1) == 0;
      float f = iPass ? (bet * S0 * __expf(-QA))
                      : (bet * I0 * __expf(QB - g * tp));
      float fm2 = __shfl(f, im2);
      float fm1 = __shfl(f, im1);
      float f1  = __shfl(f, ip1);
      float f2  = __shfl(f, ip2);
      float f3  = __shfl(f, ip3);
      float e;
      if (p == 0)          e = 9.0f*f + 19.0f*f1 - 5.0f*f2 + f3;     // AM start
      else if (p < M - 1)  e = 13.0f*(f + f1) - fm1 - f2;            // interior
      else if (p == M - 1) e = fm2 - 5.0f*fm1 + 19.0f*f + 9.0f*f1;   // AM end
      else                 e = 0.0f;                                 // lane M
      e *= c24;
      float incl = e;
#pragma unroll
      for (int off = 1; off < 16; off <<= 1) {
        float w = __shfl_up(incl, off);
        if (p >= off) incl += w;
      }
      float Q = incl - e;                    // exclusive prefix = Q at knot p
      if (iPass) QB = Q; else QA = Q;
    }
    Ik[p] = I0 * __expf(QB - g * tp);        // I at knot p (exp folded here)
  }
  __syncthreads();

  // ---- output slice: cubic-Lagrange interp of Ik (no exp) ----
  const float scale = (float)M / (float)T;
  int o0 = blockIdx.x * OTILE + tid * OVPT;
  float r[OVPT];
#pragma unroll
  for (int u = 0; u < OVPT; ++u) {
    int i = o0 + u;
    float pos = (float)(i + 1) * scale;            // (0, M]
    int js = (int)pos - 1;
    js = js < 0 ? 0 : (js > M - 3 ? M - 3 : js);   // [0, 12]
    float x = pos - (float)js;                     // [0, 3]
    float xm1 = x - 1.0f, xm2 = x - 2.0f, xm3 = x - 3.0f;
    float w0 = -(xm1 * xm2 * xm3) * (1.0f / 6.0f);
    float w1 =  (x   * xm2 * xm3) * 0.5f;
    float w2 = -(x   * xm1 * xm3) * 0.5f;
    float w3 =  (x   * xm1 * xm2) * (1.0f / 6.0f);
    r[u] = w0 * Ik[js]     + w1 * Ik[js + 1]
         + w2 * Ik[js + 2] + w3 * Ik[js + 3];
  }
  if (o0 + OVPT <= T) {
    *(float4*)(out + o0) = make_float4(r[0], r[1], r[2], r[3]);
  } else {
#pragma unroll
    for (int u = 0; u < OVPT; ++u) {
      int i = o0 + u;
      if (i < T) out[i] = r[u];
    }
  }
}

extern "C" void kernel_launch(void* const* d_in, const int* in_sizes, int n_in,
                              void* d_out, int out_size, void* d_ws, size_t ws_size,
                              hipStream_t stream) {
  const float* I0 = (const float*)d_in[1];
  const float* W1 = (const float*)d_in[2];
  const float* b1 = (const float*)d_in[3];
  const float* W2 = (const float*)d_in[4];
  const float* b2 = (const float*)d_in[5];
  const float* W3 = (const float*)d_in[6];
  const float* b3 = (const float*)d_in[7];
  const float* gp = (const float*)d_in[8];
  float* out = (float*)d_out;
  int T = in_sizes[0];

  int blocks = (T + OTILE - 1) / OTILE;            // 245
  hipLaunchKernelGGL(sir_onekernel, dim3(blocks), dim3(TPB), 0, stream,
                     I0, W1, b1, W2, b2, W3, b3, gp, out, T);
}

// Round 16
// 11.322 us; speedup vs baseline: 1.0796x; 1.0796x over previous
//
#include <hip/hip_runtime.h>

static constexpr int HID = 64;
static constexpr int M   = 15;            // intervals; knots 0..15
static constexpr int NK  = 16;
static constexpr int H1S = 68;            // h1L stride: 64 + 4 pad (bank spread)
static constexpr int TPB = 512;           // 8 waves = 2/SIMD
static constexpr int OVPT  = 4;           // outputs per thread
static constexpr int OTILE = TPB * OVPT;  // 2048 outputs per block

__device__ __forceinline__ float softplusf(float x) {
  return (x > 20.0f) ? x : log1pf(expf(x));
}

// fast tanh via hardware exp + rcp: tanh(x) = 1 - 2/(e^{2x}+1). rel err ~1e-7.
__device__ __forceinline__ float fast_tanhf(float x) {
  float e = __expf(2.0f * x);
  return 1.0f - 2.0f * __builtin_amdgcn_rcpf(e + 1.0f);
}

// ONE kernel, 245 blocks x 512 threads — the measured-best R14 structure
// (reverted from R15's global-W2 experiment, which exposed L2 latency).
//  1. W2 -> regs FIRST (HBM latency hides under layer-1), then ds_write to
//     LDS; GEMM reads W2 via ~12-cycle pipelined LDS b128.
//  2. layer 1 on threads 0..255: thread = (knot = tid>>4, k0 = 4*(tid&15)),
//     h1 stored transposed+padded h1L[knot*68+k], b128 writes.
//  3. layer2+3 on threads 0..255: thread = (knot kg, units j0..j0+3); per
//     4-k chunk: 1 h1 b128 broadcast + 4 W2 b128 (2-way aliased = free).
//  4. 16-lane Picard: 7 half-passes, 4th-order cumulative quadrature,
//     writes Ik[p] = I0*exp(Q_I(t_p) - g*t_p) to LDS.
//  5. all 512 threads: cubic-Lagrange interp of Ik (no exp), float4 stores.
__global__ void __launch_bounds__(TPB)
sir_onekernel(const float* __restrict__ I_init,
              const float* __restrict__ W1, const float* __restrict__ b1,
              const float* __restrict__ W2, const float* __restrict__ b2,
              const float* __restrict__ W3, const float* __restrict__ b3,
              const float* __restrict__ gamma_param,
              float* __restrict__ out, int T) {
  __shared__ float W2s[HID * HID];   // 16 KB
  __shared__ float h1L[NK * H1S];    // 4.3 KB, [knot][k] padded
  __shared__ float beta_s[NK];
  __shared__ float Ik[NK];

  const int tid = threadIdx.x;
  const float h = 1.0f / (float)M;

  // ---- issue W2 loads into regs (latency hides under layer-1) ----
  float4 wA = ((const float4*)W2)[tid];
  float4 wB = ((const float4*)W2)[tid + 512];

  // ---- layer 1 on threads 0..255: (knot = tid>>4, k0 = 4*(tid&15)) ----
  if (tid < 256) {
    const int knot = tid >> 4;                 // [0,16)
    const int k0   = (tid & 15) * 4;           // [0,64)
    const float tv = (float)knot * h;
    float4 w1 = *(const float4*)(W1 + k0);
    float4 bb = *(const float4*)(b1 + k0);
    float4 hv;
    hv.x = fast_tanhf(fmaf(tv, w1.x, bb.x));
    hv.y = fast_tanhf(fmaf(tv, w1.y, bb.y));
    hv.z = fast_tanhf(fmaf(tv, w1.z, bb.z));
    hv.w = fast_tanhf(fmaf(tv, w1.w, bb.w));
    *(float4*)(h1L + knot * H1S + k0) = hv;
  }

  // ---- complete W2 staging, then one barrier covers both ----
  ((float4*)W2s)[tid]       = wA;
  ((float4*)W2s)[tid + 512] = wB;
  __syncthreads();

  // ---- layers 2+3 on threads 0..255: (knot kg, units j0..j0+3) ----
  if (tid < 256) {
    const int kg = tid >> 4;            // [0,16)
    const int jq = tid & 15;
    const int j0 = jq * 4;
    float4 bb2 = *(const float4*)(b2 + j0);
    float z0 = bb2.x, z1 = bb2.y, z2 = bb2.z, z3 = bb2.w;
    const float* h1row = h1L + kg * H1S;
#pragma unroll 4
    for (int kc = 0; kc < HID; kc += 4) {
      float4 ha = *(const float4*)(h1row + kc);            // broadcast
      float4 w0v = *(const float4*)(W2s + (kc + 0) * HID + j0);
      float4 w1v = *(const float4*)(W2s + (kc + 1) * HID + j0);
      float4 w2v = *(const float4*)(W2s + (kc + 2) * HID + j0);
      float4 w3v_ = *(const float4*)(W2s + (kc + 3) * HID + j0);
      z0 = fmaf(ha.x, w0v.x, z0); z1 = fmaf(ha.x, w0v.y, z1);
      z2 = fmaf(ha.x, w0v.z, z2); z3 = fmaf(ha.x, w0v.w, z3);
      z0 = fmaf(ha.y, w1v.x, z0); z1 = fmaf(ha.y, w1v.y, z1);
      z2 = fmaf(ha.y, w1v.z, z2); z3 = fmaf(ha.y, w1v.w, z3);
      z0 = fmaf(ha.z, w2v.x, z0); z1 = fmaf(ha.z, w2v.y, z1);
      z2 = fmaf(ha.z, w2v.z, z2); z3 = fmaf(ha.z, w2v.w, z3);
      z0 = fmaf(ha.w, w3v_.x, z0); z1 = fmaf(ha.w, w3v_.y, z1);
      z2 = fmaf(ha.w, w3v_.z, z2); z3 = fmaf(ha.w, w3v_.w, z3);
    }
    float4 w3v = *(const float4*)(W3 + j0);
    float acc = fast_tanhf(z0) * w3v.x + fast_tanhf(z1) * w3v.y
              + fast_tanhf(z2) * w3v.z + fast_tanhf(z3) * w3v.w;
    acc += __shfl_xor(acc, 1);
    acc += __shfl_xor(acc, 2);
    acc += __shfl_xor(acc, 4);
    acc += __shfl_xor(acc, 8);
    if (jq == 0) beta_s[kg] = softplusf(acc + b3[0]);
  }
  __syncthreads();

  // ---- Picard on lanes 0..15 (serial path, others wait) ----
  if (tid < 16) {
    const float I0 = I_init[0];
    const float g  = softplusf(gamma_param[0]);
    const float S0 = 1.0f - I0;
    const int p = tid;
    const float tp = (float)p * h;
    const float bet = beta_s[p];
    const float c24 = h * (1.0f / 24.0f);
    float QA = 0.0f, QB = 0.0f;
    const int im2 = p >= 2 ? p - 2 : 0;
    const int im1 = p >= 1 ? p - 1 : 0;
    const int ip1 = p <= M - 1 ? p + 1 : M;
    const int ip2 = p <= M - 2 ? p + 2 : M;
    const int ip3 = p <= M - 3 ? p + 3 : M;
    for (int ph = 0; ph < 7; ++ph) {
      const bool iPass = (ph & 1) == 0;
      float f = iPass ? (bet * S0 * __expf(-QA))
                      : (bet * I0 * __expf(QB - g * tp));
      float fm2 = __shfl(f, im2);
      float fm1 = __shfl(f, im1);
      float f1  = __shfl(f, ip1);
      float f2  = __shfl(f, ip2);
      float f3  = __shfl(f, ip3);
      float e;
      if (p == 0)          e = 9.0f*f + 19.0f*f1 - 5.0f*f2 + f3;     // AM start
      else if (p < M - 1)  e = 13.0f*(f + f1) - fm1 - f2;            // interior
      else if (p == M - 1) e = fm2 - 5.0f*fm1 + 19.0f*f + 9.0f*f1;   // AM end
      else                 e = 0.0f;                                 // lane M
      e *= c24;
      float incl = e;
#pragma unroll
      for (int off = 1; off < 16; off <<= 1) {
        float w = __shfl_up(incl, off);
        if (p >= off) incl += w;
      }
      float Q = incl - e;                    // exclusive prefix = Q at knot p
      if (iPass) QB = Q; else QA = Q;
    }
    Ik[p] = I0 * __expf(QB - g * tp);        // I at knot p (exp folded here)
  }
  __syncthreads();

  // ---- output slice: cubic-Lagrange interp of Ik (no exp) ----
  const float scale = (float)M / (float)T;
  int o0 = blockIdx.x * OTILE + tid * OVPT;
  float r[OVPT];
#pragma unroll
  for (int u = 0; u < OVPT; ++u) {
    int i = o0 + u;
    float pos = (float)(i + 1) * scale;            // (0, M]
    int js = (int)pos - 1;
    js = js < 0 ? 0 : (js > M - 3 ? M - 3 : js);   // [0, 12]
    float x = pos - (float)js;                     // [0, 3]
    float xm1 = x - 1.0f, xm2 = x - 2.0f, xm3 = x - 3.0f;
    float w0 = -(xm1 * xm2 * xm3) * (1.0f / 6.0f);
    float w1 =  (x   * xm2 * xm3) * 0.5f;
    float w2 = -(x   * xm1 * xm3) * 0.5f;
    float w3 =  (x   * xm1 * xm2) * (1.0f / 6.0f);
    r[u] = w0 * Ik[js]     + w1 * Ik[js + 1]
         + w2 * Ik[js + 2] + w3 * Ik[js + 3];
  }
  if (o0 + OVPT <= T) {
    *(float4*)(out + o0) = make_float4(r[0], r[1], r[2], r[3]);
  } else {
#pragma unroll
    for (int u = 0; u < OVPT; ++u) {
      int i = o0 + u;
      if (i < T) out[i] = r[u];
    }
  }
}

extern "C" void kernel_launch(void* const* d_in, const int* in_sizes, int n_in,
                              void* d_out, int out_size, void* d_ws, size_t ws_size,
                              hipStream_t stream) {
  const float* I0 = (const float*)d_in[1];
  const float* W1 = (const float*)d_in[2];
  const float* b1 = (const float*)d_in[3];
  const float* W2 = (const float*)d_in[4];
  const float* b2 = (const float*)d_in[5];
  const float* W3 = (const float*)d_in[6];
  const float* b3 = (const float*)d_in[7];
  const float* gp = (const float*)d_in[8];
  float* out = (float*)d_out;
  int T = in_sizes[0];

  int blocks = (T + OTILE - 1) / OTILE;            // 245
  hipLaunchKernelGGL(sir_onekernel, dim3(blocks), dim3(TPB), 0, stream,
                     I0, W1, b1, W2, b2, W3, b3, gp, out, T);
}